// Round 6
// baseline (1872.340 us; speedup 1.0000x reference)
//
#include <hip/hip_runtime.h>
#include <hip/hip_bf16.h>

#define HH 100      // hidden size
#define HP 112      // padded hidden (7*16)
#define MT 7        // 16-wide tiles over hidden
#define KS 120      // row stride (bf16 elems) of LDS W2 buffers
#define RB 64       // rows per block (4 waves * 16 rows)
#define LL 3

typedef __attribute__((ext_vector_type(4))) short bf16x4;
typedef __attribute__((ext_vector_type(4))) float f32x4;

// D = A(16x16) @ B(16x16) + C via v_mfma_f32_16x16x16_bf16 (gfx950).
// A: lane m=l&15 holds k=(l>>4)*4+i ; B: lane n=l&15 holds k=(l>>4)*4+i ;
// C/D: col=l&15, row=(l>>4)*4+reg.  Intrinsic (not asm) so the compiler
// inserts MFMA<->VALU hazard wait-states (R3's NaN).
__device__ __forceinline__ f32x4 mfma16(bf16x4 a, bf16x4 b, f32x4 c) {
#if __has_builtin(__builtin_amdgcn_mfma_f32_16x16x16bf16_1k)
    return __builtin_amdgcn_mfma_f32_16x16x16bf16_1k(a, b, c, 0, 0, 0);
#else
    asm volatile("s_nop 1\n\t"
                 "v_mfma_f32_16x16x16_bf16 %0, %1, %2, %0\n\t"
                 "s_nop 7\n\t"
                 "s_nop 7"
                 : "+v"(c) : "v"(a), "v"(b));
    return c;
#endif
}

__device__ __forceinline__ short f2b(float f) {
    union { __hip_bfloat16 h; short s; } u;
    u.h = __float2bfloat16(f);
    return u.s;
}

// 16 rows per wave (R5 spilled at 32 rows/wave: arch-VGPR live set > 128).
__global__ __launch_bounds__(256, 2) void sympnet_kernel(
    const float* __restrict__ z,   const float* __restrict__ t,
    const float* __restrict__ Wq1, const float* __restrict__ bq1,
    const float* __restrict__ Wq2, const float* __restrict__ bq2,
    const float* __restrict__ wq3,
    const float* __restrict__ Wp1, const float* __restrict__ bp1,
    const float* __restrict__ Wp2, const float* __restrict__ bp2,
    const float* __restrict__ wp3,
    float* __restrict__ out)
{
    __shared__ short  sW2b[HP * KS];   // W2[j][k] bf16, zero-padded
    __shared__ short  sW2T[HP * KS];   // W2^T[k'][j] bf16, zero-padded
    __shared__ float4 sW1b[HP];        // (W1[k][0],W1[k][1],W1[k][2],b1[k]), zero-padded
    __shared__ float2 sb2w3[HP];       // (b2[j], w3[j]), zero-padded
    __shared__ float4 sState[RB];      // (q0,q1,p0,p1) per row
    __shared__ float  sT[RB];

    const int tid = threadIdx.x;
    const int m   = tid & 15;          // lane & 15
    const int g   = (tid >> 4) & 3;    // lane-group within wave
    const int waveRow = (tid >> 6) * 16;
    const int gbase   = blockIdx.x * RB;

    if (tid < RB) {
        sState[tid] = reinterpret_cast<const float4*>(z)[gbase + tid];
        sT[tid]     = t[gbase + tid];
    }

    #pragma unroll 1
    for (int layer = 0; layer < LL; ++layer) {
      #pragma unroll 1
      for (int pot = 0; pot < 2; ++pot) {
        const float* gW2 = (pot ? Wp2 : Wq2) + layer * (HH * HH);
        const float* gW1 = (pot ? Wp1 : Wq1) + layer * (HH * 3);
        const float* gb1 = (pot ? bp1 : bq1) + layer * HH;
        const float* gb2 = (pot ? bp2 : bq2) + layer * HH;
        const float* gw3 = (pot ? wp3 : wq3) + layer * HH;

        __syncthreads();   // prior stage done with weight buffers (also covers init)

        // ---- stage sW2b (coalesced) + small weights ----
        #pragma unroll 1
        for (int idx = tid; idx < HP * 30; idx += 256) {
            const int j  = idx / 30;
            const int kc = idx - j * 30;
            bf16x4 v = {0, 0, 0, 0};
            if (j < HH && kc < 25) {
                const float4 w = reinterpret_cast<const float4*>(gW2)[j * 25 + kc];
                v[0] = f2b(w.x); v[1] = f2b(w.y); v[2] = f2b(w.z); v[3] = f2b(w.w);
            }
            *reinterpret_cast<bf16x4*>(&sW2b[j * KS + 4 * kc]) = v;
        }
        if (tid < HP) {
            float4 w  = make_float4(0.f, 0.f, 0.f, 0.f);
            float2 bw = make_float2(0.f, 0.f);
            if (tid < HH) {
                w  = make_float4(gW1[tid * 3], gW1[tid * 3 + 1], gW1[tid * 3 + 2], gb1[tid]);
                bw = make_float2(gb2[tid], gw3[tid]);
            }
            sW1b[tid]  = w;
            sb2w3[tid] = bw;
        }
        __syncthreads();

        // ---- transpose sW2b -> sW2T in LDS ----
        #pragma unroll 1
        for (int idx = tid; idx < HP * 30; idx += 256) {
            const int kp = idx % HP;
            const int jc = idx / HP;        // 0..29
            bf16x4 v;
            #pragma unroll
            for (int i = 0; i < 4; ++i) {
                const int j = 4 * jc + i;
                v[i] = (j < HP) ? sW2b[j * KS + kp] : (short)0;
            }
            *reinterpret_cast<bf16x4*>(&sW2T[kp * KS + 4 * jc]) = v;
        }
        __syncthreads();

        // ---- compute: wave owns 16 rows ----
        const float4 s0 = sState[waveRow + m];
        const float tr0 = sT[waveRow + m];
        const float x00 = pot ? s0.z : s0.x, x01 = pot ? s0.w : s0.y;

        float dsav0 = 0.f, dsav1 = 0.f;
        float df0 = 0.f, df1 = 0.f;

        #pragma unroll 1
        for (int e = 0; e < 2; ++e) {
          const float xt0 = e ? 0.f : tr0;

          // ---- stage 1: sin(h1) straight into pass-1 B-frag layout ----
          bf16x4 sf[MT];
          #pragma unroll
          for (int mt = 0; mt < MT; ++mt) {
            #pragma unroll
            for (int r = 0; r < 4; ++r) {
              const int k = 16 * mt + 4 * g + r;
              const float4 w = sW1b[k];
              const float h0 = __builtin_fmaf(w.x, x00,
                               __builtin_fmaf(w.y, x01,
                               __builtin_fmaf(w.z, xt0, w.w)));
              sf[mt][r] = f2b(__sinf(h0));
            }
          }

          // pass 1 (transposed): H2^T[j][row] = W2 @ S1^T
          f32x4 acc[MT];
          #pragma unroll
          for (int mt = 0; mt < MT; ++mt) acc[mt] = (f32x4)0.f;
          #pragma unroll
          for (int kt = 0; kt < MT; ++kt) {
            #pragma unroll
            for (int mt = 0; mt < MT; ++mt) {
              const bf16x4 a = *reinterpret_cast<const bf16x4*>(
                  &sW2b[(16 * mt + m) * KS + 16 * kt + 4 * g]);
              acc[mt] = mfma16(a, sf[kt], acc[mt]);
            }
          }

          // g2 = cos(h2+b2)*w3 ; lands directly in pass-2 B-frag layout (reuse sf)
          #pragma unroll
          for (int mt = 0; mt < MT; ++mt) {
            #pragma unroll
            for (int r = 0; r < 4; ++r) {
              const int j = 16 * mt + 4 * g + r;
              const float2 bw = sb2w3[j];
              sf[mt][r] = f2b(__cosf(acc[mt][r] + bw.x) * bw.y);
            }
          }

          // pass 2 (transposed): G1^T[k'][row] = W2^T @ G2^T (reuse acc)
          #pragma unroll
          for (int mt = 0; mt < MT; ++mt) acc[mt] = (f32x4)0.f;
          #pragma unroll
          for (int kt = 0; kt < MT; ++kt) {
            #pragma unroll
            for (int mt = 0; mt < MT; ++mt) {
              const bf16x4 a = *reinterpret_cast<const bf16x4*>(
                  &sW2T[(16 * mt + m) * KS + 16 * kt + 4 * g]);
              acc[mt] = mfma16(a, sf[kt], acc[mt]);
            }
          }

          // epilogue: recompute h1/cos(h1); delta[row][c] = sum_k G1*cos*W1[k][c]
          float pc0 = 0.f, pc1 = 0.f;
          #pragma unroll
          for (int mt = 0; mt < MT; ++mt) {
            #pragma unroll
            for (int r = 0; r < 4; ++r) {
              const int k = 16 * mt + 4 * g + r;
              const float4 w = sW1b[k];
              const float h0 = __builtin_fmaf(w.x, x00,
                               __builtin_fmaf(w.y, x01,
                               __builtin_fmaf(w.z, xt0, w.w)));
              const float e0v = acc[mt][r] * __cosf(h0);
              pc0 = __builtin_fmaf(e0v, w.x, pc0);
              pc1 = __builtin_fmaf(e0v, w.y, pc1);
            }
          }
          pc0 += __shfl_xor(pc0, 16); pc0 += __shfl_xor(pc0, 32);
          pc1 += __shfl_xor(pc1, 16); pc1 += __shfl_xor(pc1, 32);

          if (e == 0) { dsav0 = pc0; dsav1 = pc1; }
          else        { df0 = dsav0 - pc0; df1 = dsav1 - pc1; }
        } // e

        // state update: lane-group 0 writes the wave's 16 rows
        if (g == 0) {
            float* sp = reinterpret_cast<float*>(&sState[waveRow + m]);
            if (pot == 0) { sp[2] -= df0; sp[3] -= df1; }
            else          { sp[0] += df0; sp[1] += df1; }
        }
      } // pot
    } // layer

    __syncthreads();
    if (tid < RB) {
        reinterpret_cast<float4*>(out)[gbase + tid] = sState[tid];
    }
}

extern "C" void kernel_launch(void* const* d_in, const int* in_sizes, int n_in,
                              void* d_out, int out_size, void* d_ws, size_t ws_size,
                              hipStream_t stream) {
    const float* z   = (const float*)d_in[0];
    const float* t   = (const float*)d_in[1];
    const float* Wq1 = (const float*)d_in[2];
    const float* bq1 = (const float*)d_in[3];
    const float* Wq2 = (const float*)d_in[4];
    const float* bq2 = (const float*)d_in[5];
    const float* wq3 = (const float*)d_in[6];
    const float* Wp1 = (const float*)d_in[7];
    const float* bp1 = (const float*)d_in[8];
    const float* Wp2 = (const float*)d_in[9];
    const float* bp2 = (const float*)d_in[10];
    const float* wp3 = (const float*)d_in[11];
    float* out = (float*)d_out;

    const int B = in_sizes[1];          // 131072 rows
    const int blocks = B / RB;          // 2048 blocks

    sympnet_kernel<<<blocks, 256, 0, stream>>>(
        z, t, Wq1, bq1, Wq2, bq2, wq3, Wp1, bp1, Wp2, bp2, wp3, out);
}

// Round 7
// 290.016 us; speedup vs baseline: 6.4560x; 6.4560x over previous
//
#include <hip/hip_runtime.h>
#include <hip/hip_bf16.h>

#define HH 100      // hidden size
#define HP 112      // padded hidden (7*16)
#define MT 7        // 16-wide tiles over hidden
#define KS 120      // row stride (bf16 elems) of LDS W2 buffers
#define RB 128      // rows per block (4 waves * 32 rows)
#define LL 3

typedef __attribute__((ext_vector_type(4))) short bf16x4;
typedef __attribute__((ext_vector_type(4))) float f32x4;

// D = A(16x16) @ B(16x16) + C via v_mfma_f32_16x16x16_bf16 (gfx950).
// A: lane m=l&15 holds k=(l>>4)*4+i ; B: lane n=l&15 holds k=(l>>4)*4+i ;
// C/D: col=l&15, row=(l>>4)*4+reg.  Intrinsic (not asm) so the compiler
// inserts MFMA<->VALU hazard wait-states (R3's NaN).
__device__ __forceinline__ f32x4 mfma16(bf16x4 a, bf16x4 b, f32x4 c) {
#if __has_builtin(__builtin_amdgcn_mfma_f32_16x16x16bf16_1k)
    return __builtin_amdgcn_mfma_f32_16x16x16bf16_1k(a, b, c, 0, 0, 0);
#else
    asm volatile("s_nop 1\n\t"
                 "v_mfma_f32_16x16x16_bf16 %0, %1, %2, %0\n\t"
                 "s_nop 7\n\t"
                 "s_nop 7"
                 : "+v"(c) : "v"(a), "v"(b));
    return c;
#endif
}

// Fence the pre-RA scheduler: without these it hoists all 49 ds_read A-frags
// per MFMA pass (~98 VGPRs in flight) -> arch-VGPR spill to scratch
// (R5/R6: 5-7 GB of HBM scratch traffic, invariant to our array sizes).
__device__ __forceinline__ void sfence() { __builtin_amdgcn_sched_barrier(0); }

__device__ __forceinline__ short f2b(float f) {
    union { __hip_bfloat16 h; short s; } u;
    u.h = __float2bfloat16(f);
    return u.s;
}

__global__ __launch_bounds__(256, 2) void sympnet_kernel(
    const float* __restrict__ z,   const float* __restrict__ t,
    const float* __restrict__ Wq1, const float* __restrict__ bq1,
    const float* __restrict__ Wq2, const float* __restrict__ bq2,
    const float* __restrict__ wq3,
    const float* __restrict__ Wp1, const float* __restrict__ bp1,
    const float* __restrict__ Wp2, const float* __restrict__ bp2,
    const float* __restrict__ wp3,
    float* __restrict__ out)
{
    __shared__ short  sW2b[HP * KS];   // W2[j][k] bf16, zero-padded
    __shared__ short  sW2T[HP * KS];   // W2^T[k'][j] bf16, zero-padded
    __shared__ float4 sW1b[HP];        // (W1[k][0],W1[k][1],W1[k][2],b1[k]), zero-padded
    __shared__ float2 sb2w3[HP];       // (b2[j], w3[j]), zero-padded
    __shared__ float4 sState[RB];      // (q0,q1,p0,p1) per row
    __shared__ float  sT[RB];

    const int tid = threadIdx.x;
    const int m   = tid & 15;          // lane & 15
    const int g   = (tid >> 4) & 3;    // lane-group within wave
    const int waveRow = (tid >> 6) * 32;
    const int gbase   = blockIdx.x * RB;

    if (tid < RB) {
        sState[tid] = reinterpret_cast<const float4*>(z)[gbase + tid];
        sT[tid]     = t[gbase + tid];
    }

    #pragma unroll 1
    for (int layer = 0; layer < LL; ++layer) {
      #pragma unroll 1
      for (int pot = 0; pot < 2; ++pot) {
        const float* gW2 = (pot ? Wp2 : Wq2) + layer * (HH * HH);
        const float* gW1 = (pot ? Wp1 : Wq1) + layer * (HH * 3);
        const float* gb1 = (pot ? bp1 : bq1) + layer * HH;
        const float* gb2 = (pot ? bp2 : bq2) + layer * HH;
        const float* gw3 = (pot ? wp3 : wq3) + layer * HH;

        __syncthreads();   // prior stage done with weight buffers (also covers init)

        // ---- stage sW2b (coalesced) + small weights ----
        #pragma unroll 1
        for (int idx = tid; idx < HP * 30; idx += 256) {
            const int j  = idx / 30;
            const int kc = idx - j * 30;
            bf16x4 v = {0, 0, 0, 0};
            if (j < HH && kc < 25) {
                const float4 w = reinterpret_cast<const float4*>(gW2)[j * 25 + kc];
                v[0] = f2b(w.x); v[1] = f2b(w.y); v[2] = f2b(w.z); v[3] = f2b(w.w);
            }
            *reinterpret_cast<bf16x4*>(&sW2b[j * KS + 4 * kc]) = v;
        }
        if (tid < HP) {
            float4 w  = make_float4(0.f, 0.f, 0.f, 0.f);
            float2 bw = make_float2(0.f, 0.f);
            if (tid < HH) {
                w  = make_float4(gW1[tid * 3], gW1[tid * 3 + 1], gW1[tid * 3 + 2], gb1[tid]);
                bw = make_float2(gb2[tid], gw3[tid]);
            }
            sW1b[tid]  = w;
            sb2w3[tid] = bw;
        }
        __syncthreads();

        // ---- transpose sW2b -> sW2T in LDS ----
        #pragma unroll 1
        for (int idx = tid; idx < HP * 30; idx += 256) {
            const int kp = idx % HP;
            const int jc = idx / HP;        // 0..29
            bf16x4 v;
            #pragma unroll
            for (int i = 0; i < 4; ++i) {
                const int j = 4 * jc + i;
                v[i] = (j < HP) ? sW2b[j * KS + kp] : (short)0;
            }
            *reinterpret_cast<bf16x4*>(&sW2T[kp * KS + 4 * jc]) = v;
        }
        __syncthreads();

        // ---- compute: wave owns 32 rows (two 16-row tiles) ----
        const float4 s0 = sState[waveRow + m];
        const float4 s1 = sState[waveRow + 16 + m];
        const float tr0 = sT[waveRow + m];
        const float tr1 = sT[waveRow + 16 + m];
        const float x00 = pot ? s0.z : s0.x, x01 = pot ? s0.w : s0.y;
        const float x10 = pot ? s1.z : s1.x, x11 = pot ? s1.w : s1.y;

        float dsav00 = 0.f, dsav01 = 0.f, dsav10 = 0.f, dsav11 = 0.f;
        float df00 = 0.f, df01 = 0.f, df10 = 0.f, df11 = 0.f;

        #pragma unroll 1
        for (int e = 0; e < 2; ++e) {
          const float xt0 = e ? 0.f : tr0;
          const float xt1 = e ? 0.f : tr1;

          // ---- stage 1: sin(h1) straight into pass-1 B-frag layout ----
          bf16x4 sf[MT][2];
          #pragma unroll
          for (int mt = 0; mt < MT; ++mt) {
            #pragma unroll
            for (int r = 0; r < 4; ++r) {
              const int k = 16 * mt + 4 * g + r;
              const float4 w = sW1b[k];
              const float h0 = __builtin_fmaf(w.x, x00,
                               __builtin_fmaf(w.y, x01,
                               __builtin_fmaf(w.z, xt0, w.w)));
              const float h1 = __builtin_fmaf(w.x, x10,
                               __builtin_fmaf(w.y, x11,
                               __builtin_fmaf(w.z, xt1, w.w)));
              sf[mt][0][r] = f2b(__sinf(h0));
              sf[mt][1][r] = f2b(__sinf(h1));
            }
            if (mt & 1) sfence();
          }
          sfence();

          // pass 1 (transposed): H2^T[j][row] = W2 @ S1^T
          f32x4 acc[MT][2];
          #pragma unroll
          for (int mt = 0; mt < MT; ++mt) { acc[mt][0] = (f32x4)0.f; acc[mt][1] = (f32x4)0.f; }
          #pragma unroll
          for (int kt = 0; kt < MT; ++kt) {
            #pragma unroll
            for (int mt = 0; mt < MT; ++mt) {
              const bf16x4 a = *reinterpret_cast<const bf16x4*>(
                  &sW2b[(16 * mt + m) * KS + 16 * kt + 4 * g]);
              acc[mt][0] = mfma16(a, sf[kt][0], acc[mt][0]);
              acc[mt][1] = mfma16(a, sf[kt][1], acc[mt][1]);
            }
            if (kt & 1) sfence();
          }
          sfence();

          // g2 = cos(h2+b2)*w3 ; lands directly in pass-2 B-frag layout (reuse sf)
          #pragma unroll
          for (int mt = 0; mt < MT; ++mt) {
            #pragma unroll
            for (int r = 0; r < 4; ++r) {
              const int j = 16 * mt + 4 * g + r;
              const float2 bw = sb2w3[j];
              sf[mt][0][r] = f2b(__cosf(acc[mt][0][r] + bw.x) * bw.y);
              sf[mt][1][r] = f2b(__cosf(acc[mt][1][r] + bw.x) * bw.y);
            }
            if (mt & 1) sfence();
          }
          sfence();

          // pass 2 (transposed): G1^T[k'][row] = W2^T @ G2^T (reuse acc)
          #pragma unroll
          for (int mt = 0; mt < MT; ++mt) { acc[mt][0] = (f32x4)0.f; acc[mt][1] = (f32x4)0.f; }
          #pragma unroll
          for (int kt = 0; kt < MT; ++kt) {
            #pragma unroll
            for (int mt = 0; mt < MT; ++mt) {
              const bf16x4 a = *reinterpret_cast<const bf16x4*>(
                  &sW2T[(16 * mt + m) * KS + 16 * kt + 4 * g]);
              acc[mt][0] = mfma16(a, sf[kt][0], acc[mt][0]);
              acc[mt][1] = mfma16(a, sf[kt][1], acc[mt][1]);
            }
            if (kt & 1) sfence();
          }
          sfence();

          // epilogue: recompute h1/cos(h1); delta[row][c] = sum_k G1*cos*W1[k][c]
          float pc00 = 0.f, pc01 = 0.f, pc10 = 0.f, pc11 = 0.f;
          #pragma unroll
          for (int mt = 0; mt < MT; ++mt) {
            #pragma unroll
            for (int r = 0; r < 4; ++r) {
              const int k = 16 * mt + 4 * g + r;
              const float4 w = sW1b[k];
              const float h0 = __builtin_fmaf(w.x, x00,
                               __builtin_fmaf(w.y, x01,
                               __builtin_fmaf(w.z, xt0, w.w)));
              const float h1 = __builtin_fmaf(w.x, x10,
                               __builtin_fmaf(w.y, x11,
                               __builtin_fmaf(w.z, xt1, w.w)));
              const float e0v = acc[mt][0][r] * __cosf(h0);
              const float e1v = acc[mt][1][r] * __cosf(h1);
              pc00 = __builtin_fmaf(e0v, w.x, pc00);
              pc01 = __builtin_fmaf(e0v, w.y, pc01);
              pc10 = __builtin_fmaf(e1v, w.x, pc10);
              pc11 = __builtin_fmaf(e1v, w.y, pc11);
            }
            if (mt & 1) sfence();
          }
          sfence();

          pc00 += __shfl_xor(pc00, 16); pc00 += __shfl_xor(pc00, 32);
          pc01 += __shfl_xor(pc01, 16); pc01 += __shfl_xor(pc01, 32);
          pc10 += __shfl_xor(pc10, 16); pc10 += __shfl_xor(pc10, 32);
          pc11 += __shfl_xor(pc11, 16); pc11 += __shfl_xor(pc11, 32);

          if (e == 0) { dsav00 = pc00; dsav01 = pc01; dsav10 = pc10; dsav11 = pc11; }
          else {
            df00 = dsav00 - pc00; df01 = dsav01 - pc01;
            df10 = dsav10 - pc10; df11 = dsav11 - pc11;
          }
        } // e

        // state update: lane-group 0 -> rows [waveRow..+15], group 1 -> [+16..+31]
        if (g < 2) {
            const float d0 = (g == 0) ? df00 : df10;
            const float d1 = (g == 0) ? df01 : df11;
            const int row  = waveRow + ((g == 1) ? 16 : 0) + m;
            float* sp = reinterpret_cast<float*>(&sState[row]);
            if (pot == 0) { sp[2] -= d0; sp[3] -= d1; }
            else          { sp[0] += d0; sp[1] += d1; }
        }
      } // pot
    } // layer

    __syncthreads();
    if (tid < RB) {
        reinterpret_cast<float4*>(out)[gbase + tid] = sState[tid];
    }
}

extern "C" void kernel_launch(void* const* d_in, const int* in_sizes, int n_in,
                              void* d_out, int out_size, void* d_ws, size_t ws_size,
                              hipStream_t stream) {
    const float* z   = (const float*)d_in[0];
    const float* t   = (const float*)d_in[1];
    const float* Wq1 = (const float*)d_in[2];
    const float* bq1 = (const float*)d_in[3];
    const float* Wq2 = (const float*)d_in[4];
    const float* bq2 = (const float*)d_in[5];
    const float* wq3 = (const float*)d_in[6];
    const float* Wp1 = (const float*)d_in[7];
    const float* bp1 = (const float*)d_in[8];
    const float* Wp2 = (const float*)d_in[9];
    const float* bp2 = (const float*)d_in[10];
    const float* wp3 = (const float*)d_in[11];
    float* out = (float*)d_out;

    const int B = in_sizes[1];          // 131072 rows
    const int blocks = B / RB;          // 1024 blocks

    sympnet_kernel<<<blocks, 256, 0, stream>>>(
        z, t, Wq1, bq1, Wq2, bq2, wq3, Wp1, bp1, Wp2, bp2, wp3, out);
}